// Round 2
// baseline (572.300 us; speedup 1.0000x reference)
//
#include <hip/hip_runtime.h>
#include <hip/hip_bf16.h>
#include <cstdint>

typedef __attribute__((ext_vector_type(8))) short bf16x8;   // 8 bf16 = 4 VGPRs
typedef __attribute__((ext_vector_type(4))) float f32x4;

static constexpr int Mdim = 8192;
static constexpr int Kdim = 4096;
static constexpr int Ndim = 4096;
static constexpr int BM = 128, BN = 128, BK = 32;

__device__ __forceinline__ void async_copy16(const void* g, void* l) {
  __builtin_amdgcn_global_load_lds(
      (const __attribute__((address_space(1))) void*)g,
      (__attribute__((address_space(3))) void*)l, 16, 0, 0);
}

// ---- fused prepass: one launch fills the machine with both tasks ----
//   blocks [0, 16384):   x fp32 -> bf16, 8 elems/thread, 16B ld/st
//   blocks [16384, 20480): w [K][N] fp32 -> bwT [N][K] bf16 sign(w),
//                          64x64 tile, LDS transpose, 16B ld + 16B st
static constexpr int CVT_BLOCKS = (Mdim * Kdim) / 2048;         // 16384
static constexpr int BIN_BLOCKS = (Kdim / 64) * (Ndim / 64);    // 4096
static constexpr int SP = 68;   // LDS row stride (bf16 elems), 8B-aligned rows

__global__ __launch_bounds__(256) void prepass_kernel(const float* __restrict__ x,
                                                      const float* __restrict__ w,
                                                      __hip_bfloat16* __restrict__ xb,
                                                      __hip_bfloat16* __restrict__ bwT) {
  __shared__ __hip_bfloat16 s[64 * SP];
  const int tid = threadIdx.x;

  if (blockIdx.x < CVT_BLOCKS) {
    // ---- x convert ----
    size_t base = ((size_t)blockIdx.x * 256 + tid) * 8;
    const float4* p = reinterpret_cast<const float4*>(x + base);
    float4 v0 = p[0], v1 = p[1];
    float vals[8] = {v0.x, v0.y, v0.z, v0.w, v1.x, v1.y, v1.z, v1.w};
    union { __hip_bfloat16 h[8]; uint4 u; } o;
    #pragma unroll
    for (int j = 0; j < 8; ++j) o.h[j] = __float2bfloat16(vals[j]);
    *reinterpret_cast<uint4*>(xb + base) = o.u;
  } else {
    // ---- w binarize + transpose ----
    int bid = blockIdx.x - CVT_BLOCKS;
    int k0 = (bid & 63) * 64;
    int n0 = (bid >> 6) * 64;
    // phase 1: coalesced float4 reads of w rows, sign -> bf16, LDS [k][n]
    #pragma unroll
    for (int r = 0; r < 4; ++r) {
      int c = r * 256 + tid;
      int k = c >> 4;
      int c4 = (c & 15) * 4;
      float4 v = *reinterpret_cast<const float4*>(w + (size_t)(k0 + k) * Ndim + n0 + c4);
      float vv[4] = {v.x, v.y, v.z, v.w};
      union { __hip_bfloat16 h[4]; uint2 u; } o;
      #pragma unroll
      for (int j = 0; j < 4; ++j) {
        float sg = (vv[j] > 0.f) ? 1.f : ((vv[j] < 0.f) ? -1.f : 0.f);
        o.h[j] = __float2bfloat16(sg);
      }
      *reinterpret_cast<uint2*>(&s[k * SP + c4]) = o.u;
    }
    __syncthreads();
    // phase 2: gather 8 contiguous k per (n), pack, 16B coalesced store
    #pragma unroll
    for (int r = 0; r < 2; ++r) {
      int c = r * 256 + tid;
      int n = c >> 3;
      int ck = (c & 7) * 8;
      union { __hip_bfloat16 h[8]; uint4 u; } o;
      #pragma unroll
      for (int j = 0; j < 8; ++j) o.h[j] = s[(ck + j) * SP + n];
      *reinterpret_cast<uint4*>(bwT + (size_t)(n0 + n) * Kdim + k0 + ck) = o.u;
    }
  }
}

// ---- main GEMM (m97 structure): A [M][K] bf16, Bt [N][K] bf16, out fp32 ----
__global__ __launch_bounds__(256) void gemm_kernel(const __hip_bfloat16* __restrict__ A,
                                                   const __hip_bfloat16* __restrict__ Bt,
                                                   const float* __restrict__ bias,
                                                   float* __restrict__ out) {
  __shared__ __hip_bfloat16 sA[BM * BK];   // [128][32], linear (global_load_lds: no pad)
  __shared__ __hip_bfloat16 sB[BN * BK];   // [128][32] of B^T
  const int tid  = threadIdx.x;
  const int bn   = blockIdx.x, bm = blockIdx.y;
  const int lane = tid & 63;
  const int wave = tid >> 6;
  const int wm   = (wave & 1) * 64;    // wave sub-tile origin in M
  const int wn   = (wave >> 1) * 64;   // ... in N
  const int lr   = lane & 15;
  const int quad = lane >> 4;

  const int c0 = tid, c1 = tid + 256;
  const int rowA0 = c0 >> 2, colA0 = (c0 & 3) * 8;
  const int rowA1 = c1 >> 2, colA1 = (c1 & 3) * 8;
  const __hip_bfloat16* gA0 = A  + (size_t)(bm * BM + rowA0) * Kdim + colA0;
  const __hip_bfloat16* gA1 = A  + (size_t)(bm * BM + rowA1) * Kdim + colA1;
  const __hip_bfloat16* gB0 = Bt + (size_t)(bn * BN + rowA0) * Kdim + colA0;
  const __hip_bfloat16* gB1 = Bt + (size_t)(bn * BN + rowA1) * Kdim + colA1;

  f32x4 acc[4][4] = {};

  for (int k0 = 0; k0 < Kdim; k0 += BK) {
    async_copy16(gA0 + k0, &sA[c0 * 8]);
    async_copy16(gA1 + k0, &sA[c1 * 8]);
    async_copy16(gB0 + k0, &sB[c0 * 8]);
    async_copy16(gB1 + k0, &sB[c1 * 8]);
    __syncthreads();

    bf16x8 af[4], bf[4];
    #pragma unroll
    for (int i = 0; i < 4; ++i)
      af[i] = *reinterpret_cast<const bf16x8*>(&sA[(wm + i * 16 + lr) * BK + quad * 8]);
    #pragma unroll
    for (int j = 0; j < 4; ++j)
      bf[j] = *reinterpret_cast<const bf16x8*>(&sB[(wn + j * 16 + lr) * BK + quad * 8]);
    #pragma unroll
    for (int i = 0; i < 4; ++i)
      #pragma unroll
      for (int j = 0; j < 4; ++j)
        acc[i][j] = __builtin_amdgcn_mfma_f32_16x16x32_bf16(af[i], bf[j], acc[i][j], 0, 0, 0);
    __syncthreads();
  }

  float bv[4];
  #pragma unroll
  for (int j = 0; j < 4; ++j) bv[j] = bias[bn * BN + wn + j * 16 + lr];
  #pragma unroll
  for (int i = 0; i < 4; ++i) {
    const size_t rowb = (size_t)(bm * BM + wm + i * 16 + quad * 4);
    #pragma unroll
    for (int j = 0; j < 4; ++j) {
      const int col = bn * BN + wn + j * 16 + lr;
      float* o = out + rowb * Ndim + col;
      #pragma unroll
      for (int r = 0; r < 4; ++r)
        o[(size_t)r * Ndim] = acc[i][j][r] + bv[j];
    }
  }
}

// ---- fallback (no workspace): fused convert/binarize staging ----
__global__ __launch_bounds__(256) void gemm_fused_kernel(const float* __restrict__ X,
                                                         const float* __restrict__ W,
                                                         const float* __restrict__ bias,
                                                         float* __restrict__ out) {
  __shared__ __hip_bfloat16 sA[BM * BK];
  __shared__ __hip_bfloat16 sB[BN * BK];   // stored [n][k]
  const int tid  = threadIdx.x;
  const int bn   = blockIdx.x, bm = blockIdx.y;
  const int lane = tid & 63;
  const int wave = tid >> 6;
  const int wm   = (wave & 1) * 64;
  const int wn   = (wave >> 1) * 64;
  const int lr   = lane & 15;
  const int quad = lane >> 4;

  f32x4 acc[4][4] = {};

  for (int k0 = 0; k0 < Kdim; k0 += BK) {
    #pragma unroll
    for (int r = 0; r < 2; ++r) {
      int c = r * 256 + tid;
      int row = c >> 2, col = (c & 3) * 8;
      const float4* p = reinterpret_cast<const float4*>(X + (size_t)(bm * BM + row) * Kdim + k0 + col);
      float4 v0 = p[0], v1 = p[1];
      float va[8] = {v0.x, v0.y, v0.z, v0.w, v1.x, v1.y, v1.z, v1.w};
      union { __hip_bfloat16 h[8]; uint4 u; } oa;
      #pragma unroll
      for (int u2 = 0; u2 < 8; ++u2) oa.h[u2] = __float2bfloat16(va[u2]);
      *reinterpret_cast<uint4*>(&sA[c * 8]) = oa.u;

      int kl = c >> 4, n8 = (c & 15) * 8;
      const float4* q = reinterpret_cast<const float4*>(W + (size_t)(k0 + kl) * Ndim + bn * BN + n8);
      float4 w0 = q[0], w1 = q[1];
      float wv[8] = {w0.x, w0.y, w0.z, w0.w, w1.x, w1.y, w1.z, w1.w};
      #pragma unroll
      for (int u2 = 0; u2 < 8; ++u2) {
        float sg = (wv[u2] > 0.f) ? 1.f : ((wv[u2] < 0.f) ? -1.f : 0.f);
        sB[(n8 + u2) * BK + kl] = __float2bfloat16(sg);
      }
    }
    __syncthreads();

    bf16x8 af[4], bf[4];
    #pragma unroll
    for (int i = 0; i < 4; ++i)
      af[i] = *reinterpret_cast<const bf16x8*>(&sA[(wm + i * 16 + lr) * BK + quad * 8]);
    #pragma unroll
    for (int j = 0; j < 4; ++j)
      bf[j] = *reinterpret_cast<const bf16x8*>(&sB[(wn + j * 16 + lr) * BK + quad * 8]);
    #pragma unroll
    for (int i = 0; i < 4; ++i)
      #pragma unroll
      for (int j = 0; j < 4; ++j)
        acc[i][j] = __builtin_amdgcn_mfma_f32_16x16x32_bf16(af[i], bf[j], acc[i][j], 0, 0, 0);
    __syncthreads();
  }

  float bv[4];
  #pragma unroll
  for (int j = 0; j < 4; ++j) bv[j] = bias[bn * BN + wn + j * 16 + lr];
  #pragma unroll
  for (int i = 0; i < 4; ++i) {
    const size_t rowb = (size_t)(bm * BM + wm + i * 16 + quad * 4);
    #pragma unroll
    for (int j = 0; j < 4; ++j) {
      const int col = bn * BN + wn + j * 16 + lr;
      float* o = out + rowb * Ndim + col;
      #pragma unroll
      for (int r = 0; r < 4; ++r)
        o[(size_t)r * Ndim] = acc[i][j][r] + bv[j];
    }
  }
}

extern "C" void kernel_launch(void* const* d_in, const int* in_sizes, int n_in,
                              void* d_out, int out_size, void* d_ws, size_t ws_size,
                              hipStream_t stream) {
  const float* x = (const float*)d_in[0];   // [8192,4096]
  const float* w = (const float*)d_in[1];   // [4096,4096]
  const float* b = (const float*)d_in[2];   // [4096]
  float* out = (float*)d_out;

  const size_t need = (size_t)Mdim * Kdim * 2 + (size_t)Ndim * Kdim * 2;  // 96 MiB
  if (ws_size >= need) {
    __hip_bfloat16* xb  = (__hip_bfloat16*)d_ws;
    __hip_bfloat16* bwT = (__hip_bfloat16*)((char*)d_ws + (size_t)Mdim * Kdim * 2);
    prepass_kernel<<<CVT_BLOCKS + BIN_BLOCKS, 256, 0, stream>>>(x, w, xb, bwT);
    gemm_kernel<<<dim3(Ndim / BN, Mdim / BM), 256, 0, stream>>>(xb, bwT, b, out);
  } else {
    gemm_fused_kernel<<<dim3(Ndim / BN, Mdim / BM), 256, 0, stream>>>(x, w, b, out);
  }
}

// Round 3
// 423.397 us; speedup vs baseline: 1.3517x; 1.3517x over previous
//
#include <hip/hip_runtime.h>
#include <hip/hip_bf16.h>
#include <cstdint>

typedef __attribute__((ext_vector_type(8))) short bf16x8;
typedef __attribute__((ext_vector_type(4))) float f32x4;
typedef __attribute__((ext_vector_type(4))) int   i32x4;

static constexpr int Mdim = 8192;
static constexpr int Kdim = 4096;
static constexpr int Ndim = 4096;
static constexpr int BM = 128, BN = 128;

__device__ __forceinline__ void async_copy16(const void* g, void* l) {
  __builtin_amdgcn_global_load_lds(
      (const __attribute__((address_space(1))) void*)g,
      (__attribute__((address_space(3))) void*)l, 16, 0, 0);
}

// ---- prepass 1: per-row absmax quantize x fp32 -> i8, store s_row ----
// 8 rows/block, 32 lanes/row, whole row held in regs (32 float4 = 128 VGPR).
__global__ __launch_bounds__(256) void quant_x_kernel(const float* __restrict__ x,
                                                      int8_t* __restrict__ xq,
                                                      float* __restrict__ srow) {
  const int tid = threadIdx.x;
  const int row = blockIdx.x * 8 + (tid >> 5);
  const int l   = tid & 31;
  const float* xr = x + (size_t)row * Kdim;
  float4 v[32];
  float m = 0.f;
  #pragma unroll
  for (int j = 0; j < 32; ++j) {
    v[j] = *reinterpret_cast<const float4*>(xr + (size_t)(j * 32 + l) * 4);
    m = fmaxf(m, fmaxf(fmaxf(fabsf(v[j].x), fabsf(v[j].y)),
                       fmaxf(fabsf(v[j].z), fabsf(v[j].w))));
  }
  #pragma unroll
  for (int s = 16; s >= 1; s >>= 1) m = fmaxf(m, __shfl_xor(m, s, 64));
  const float rs = (m > 0.f) ? (127.0f / m) : 0.f;
  if (l == 0) srow[row] = m * (1.0f / 127.0f);
  uint32_t* xq32 = reinterpret_cast<uint32_t*>(xq + (size_t)row * Kdim);
  #pragma unroll
  for (int j = 0; j < 32; ++j) {
    int a0 = (int)rintf(v[j].x * rs), a1 = (int)rintf(v[j].y * rs);
    int a2 = (int)rintf(v[j].z * rs), a3 = (int)rintf(v[j].w * rs);
    uint32_t p = (uint32_t)(a0 & 255) | ((uint32_t)(a1 & 255) << 8) |
                 ((uint32_t)(a2 & 255) << 16) | ((uint32_t)(a3 & 255) << 24);
    xq32[j * 32 + l] = p;
  }
}

// ---- prepass 2: w [K][N] fp32 -> wsT [N][K] i8 = sign(w), LDS transpose ----
__global__ __launch_bounds__(256) void sign_w_kernel(const float* __restrict__ w,
                                                     int8_t* __restrict__ wsT) {
  __shared__ int8_t t[64 * 68];   // 68-byte row stride (4-aligned, spreads banks)
  const int bid = blockIdx.x;
  const int k0 = (bid & 63) * 64;
  const int n0 = (bid >> 6) * 64;
  const int tid = threadIdx.x;
  #pragma unroll
  for (int r = 0; r < 4; ++r) {
    int c  = r * 256 + tid;        // [0,1024) covers 64k x 64n / 4-wide
    int k  = c >> 4;
    int n4 = (c & 15) * 4;
    float4 v = *reinterpret_cast<const float4*>(w + (size_t)(k0 + k) * Ndim + n0 + n4);
    int s0 = (v.x > 0.f) - (v.x < 0.f);
    int s1 = (v.y > 0.f) - (v.y < 0.f);
    int s2 = (v.z > 0.f) - (v.z < 0.f);
    int s3 = (v.w > 0.f) - (v.w < 0.f);
    uint32_t p = (uint32_t)(s0 & 255) | ((uint32_t)(s1 & 255) << 8) |
                 ((uint32_t)(s2 & 255) << 16) | ((uint32_t)(s3 & 255) << 24);
    *reinterpret_cast<uint32_t*>(&t[k * 68 + n4]) = p;
  }
  __syncthreads();
  const int n  = tid & 63;          // 64 lanes -> 64 distinct n: 4-way LDS aliasing max
  const int ck = (tid >> 6) * 16;
  union { int8_t b[16]; uint4 u; } o;
  #pragma unroll
  for (int j = 0; j < 16; ++j) o.b[j] = t[(ck + j) * 68 + n];
  *reinterpret_cast<uint4*>(wsT + (size_t)(n0 + n) * Kdim + k0 + ck) = o.u;
}

// ---- main GEMM, i8 (m97 structure, BK=64 bytes): A [M][K] i8, Bt [N][K] i8 ----
__global__ __launch_bounds__(256) void gemm_i8_kernel(const int8_t* __restrict__ A,
                                                      const int8_t* __restrict__ Bt,
                                                      const float* __restrict__ srow,
                                                      const float* __restrict__ bias,
                                                      float* __restrict__ out) {
  __shared__ int8_t sA[BM * 64];   // [128][64B], linear for global_load_lds
  __shared__ int8_t sB[BN * 64];
  const int tid  = threadIdx.x;
  const int bn   = blockIdx.x, bm = blockIdx.y;
  const int lane = tid & 63;
  const int wave = tid >> 6;
  const int wm   = (wave & 1) * 64;
  const int wn   = (wave >> 1) * 64;
  const int lr   = lane & 15;
  const int quad = lane >> 4;

  // staging: 16B chunks; 512 chunks cover 128 rows x 64 bytes
  const int c0 = tid, c1 = tid + 256;
  const int row0 = c0 >> 2, col0 = (c0 & 3) * 16;
  const int row1 = c1 >> 2, col1 = (c1 & 3) * 16;
  const int8_t* gA0 = A  + (size_t)(bm * BM + row0) * Kdim + col0;
  const int8_t* gA1 = A  + (size_t)(bm * BM + row1) * Kdim + col1;
  const int8_t* gB0 = Bt + (size_t)(bn * BN + row0) * Kdim + col0;
  const int8_t* gB1 = Bt + (size_t)(bn * BN + row1) * Kdim + col1;

  i32x4 acc[4][4] = {};

  for (int k0 = 0; k0 < Kdim; k0 += 64) {
    async_copy16(gA0 + k0, &sA[c0 * 16]);
    async_copy16(gA1 + k0, &sA[c1 * 16]);
    async_copy16(gB0 + k0, &sB[c0 * 16]);
    async_copy16(gB1 + k0, &sB[c1 * 16]);
    __syncthreads();

    i32x4 af[4], bf[4];
    #pragma unroll
    for (int i = 0; i < 4; ++i)
      af[i] = *reinterpret_cast<const i32x4*>(&sA[(wm + i * 16 + lr) * 64 + quad * 16]);
    #pragma unroll
    for (int j = 0; j < 4; ++j)
      bf[j] = *reinterpret_cast<const i32x4*>(&sB[(wn + j * 16 + lr) * 64 + quad * 16]);
    #pragma unroll
    for (int i = 0; i < 4; ++i)
      #pragma unroll
      for (int j = 0; j < 4; ++j)
        acc[i][j] = __builtin_amdgcn_mfma_i32_16x16x64_i8(af[i], bf[j], acc[i][j], 0, 0, 0);
    __syncthreads();
  }

  // epilogue: C/D layout col=lane&15, row=quad*4+reg; out = acc*s_row + bias
  float bv[4];
  #pragma unroll
  for (int j = 0; j < 4; ++j) bv[j] = bias[bn * BN + wn + j * 16 + lr];
  #pragma unroll
  for (int i = 0; i < 4; ++i) {
    const int rowb = bm * BM + wm + i * 16 + quad * 4;
    float sv[4];
    #pragma unroll
    for (int r = 0; r < 4; ++r) sv[r] = srow[rowb + r];
    #pragma unroll
    for (int j = 0; j < 4; ++j) {
      const int col = bn * BN + wn + j * 16 + lr;
      float* o = out + (size_t)rowb * Ndim + col;
      #pragma unroll
      for (int r = 0; r < 4; ++r)
        o[(size_t)r * Ndim] = (float)acc[i][j][r] * sv[r] + bv[j];
    }
  }
}

// ---- fallback (no workspace): fused bf16 convert/binarize staging ----
__global__ __launch_bounds__(256) void gemm_fused_kernel(const float* __restrict__ X,
                                                         const float* __restrict__ W,
                                                         const float* __restrict__ bias,
                                                         float* __restrict__ out) {
  __shared__ __hip_bfloat16 sA[BM * 32];
  __shared__ __hip_bfloat16 sB[BN * 32];
  const int tid  = threadIdx.x;
  const int bn   = blockIdx.x, bm = blockIdx.y;
  const int lane = tid & 63;
  const int wave = tid >> 6;
  const int wm   = (wave & 1) * 64;
  const int wn   = (wave >> 1) * 64;
  const int lr   = lane & 15;
  const int quad = lane >> 4;

  f32x4 acc[4][4] = {};

  for (int k0 = 0; k0 < Kdim; k0 += 32) {
    #pragma unroll
    for (int r = 0; r < 2; ++r) {
      int c = r * 256 + tid;
      int row = c >> 2, col = (c & 3) * 8;
      const float4* p = reinterpret_cast<const float4*>(X + (size_t)(bm * BM + row) * Kdim + k0 + col);
      float4 v0 = p[0], v1 = p[1];
      float va[8] = {v0.x, v0.y, v0.z, v0.w, v1.x, v1.y, v1.z, v1.w};
      union { __hip_bfloat16 h[8]; uint4 u; } oa;
      #pragma unroll
      for (int u2 = 0; u2 < 8; ++u2) oa.h[u2] = __float2bfloat16(va[u2]);
      *reinterpret_cast<uint4*>(&sA[c * 8]) = oa.u;

      int kl = c >> 4, n8 = (c & 15) * 8;
      const float4* q = reinterpret_cast<const float4*>(W + (size_t)(k0 + kl) * Ndim + bn * BN + n8);
      float4 w0 = q[0], w1 = q[1];
      float wv[8] = {w0.x, w0.y, w0.z, w0.w, w1.x, w1.y, w1.z, w1.w};
      #pragma unroll
      for (int u2 = 0; u2 < 8; ++u2) {
        float sg = (wv[u2] > 0.f) ? 1.f : ((wv[u2] < 0.f) ? -1.f : 0.f);
        sB[(n8 + u2) * 32 + kl] = __float2bfloat16(sg);
      }
    }
    __syncthreads();

    bf16x8 af[4], bf[4];
    #pragma unroll
    for (int i = 0; i < 4; ++i)
      af[i] = *reinterpret_cast<const bf16x8*>(&sA[(wm + i * 16 + lr) * 32 + quad * 8]);
    #pragma unroll
    for (int j = 0; j < 4; ++j)
      bf[j] = *reinterpret_cast<const bf16x8*>(&sB[(wn + j * 16 + lr) * 32 + quad * 8]);
    #pragma unroll
    for (int i = 0; i < 4; ++i)
      #pragma unroll
      for (int j = 0; j < 4; ++j)
        acc[i][j] = __builtin_amdgcn_mfma_f32_16x16x32_bf16(af[i], bf[j], acc[i][j], 0, 0, 0);
    __syncthreads();
  }

  float bv[4];
  #pragma unroll
  for (int j = 0; j < 4; ++j) bv[j] = bias[bn * BN + wn + j * 16 + lr];
  #pragma unroll
  for (int i = 0; i < 4; ++i) {
    const size_t rowb = (size_t)(bm * BM + wm + i * 16 + quad * 4);
    #pragma unroll
    for (int j = 0; j < 4; ++j) {
      const int col = bn * BN + wn + j * 16 + lr;
      float* o = out + rowb * Ndim + col;
      #pragma unroll
      for (int r = 0; r < 4; ++r)
        o[(size_t)r * Ndim] = acc[i][j][r] + bv[j];
    }
  }
}

extern "C" void kernel_launch(void* const* d_in, const int* in_sizes, int n_in,
                              void* d_out, int out_size, void* d_ws, size_t ws_size,
                              hipStream_t stream) {
  const float* x = (const float*)d_in[0];   // [8192,4096]
  const float* w = (const float*)d_in[1];   // [4096,4096]
  const float* b = (const float*)d_in[2];   // [4096]
  float* out = (float*)d_out;

  const size_t xq_bytes = (size_t)Mdim * Kdim;        // 32 MiB
  const size_t wt_bytes = (size_t)Ndim * Kdim;        // 16 MiB
  const size_t sr_bytes = (size_t)Mdim * sizeof(float);
  const size_t need = xq_bytes + wt_bytes + sr_bytes;

  if (ws_size >= need) {
    int8_t* xq  = (int8_t*)d_ws;
    int8_t* wsT = (int8_t*)((char*)d_ws + xq_bytes);
    float* srow = (float*)((char*)d_ws + xq_bytes + wt_bytes);
    quant_x_kernel<<<Mdim / 8, 256, 0, stream>>>(x, xq, srow);
    sign_w_kernel<<<(Kdim / 64) * (Ndim / 64), 256, 0, stream>>>(w, wsT);
    gemm_i8_kernel<<<dim3(Ndim / BN, Mdim / BM), 256, 0, stream>>>(xq, wsT, srow, b, out);
  } else {
    gemm_fused_kernel<<<dim3(Ndim / BN, Mdim / BM), 256, 0, stream>>>(x, w, b, out);
  }
}

// Round 4
// 409.010 us; speedup vs baseline: 1.3992x; 1.0352x over previous
//
#include <hip/hip_runtime.h>
#include <hip/hip_bf16.h>
#include <cstdint>

typedef __attribute__((ext_vector_type(8))) short bf16x8;
typedef __attribute__((ext_vector_type(4))) float f32x4;
typedef __attribute__((ext_vector_type(4))) int   i32x4;
typedef __attribute__((ext_vector_type(16))) int  i32x16;

static constexpr int Mdim = 8192;
static constexpr int Kdim = 4096;
static constexpr int Ndim = 4096;
static constexpr int BM = 128, BN = 128;
static constexpr int BKB = 128;   // K-bytes per iteration (i8 => 128 k-elems)

__device__ __forceinline__ void async_copy16(const void* g, void* l) {
  __builtin_amdgcn_global_load_lds(
      (const __attribute__((address_space(1))) void*)g,
      (__attribute__((address_space(3))) void*)l, 16, 0, 0);
}

// ---- prepass 1: per-row absmax quantize x fp32 -> i8, store s_row ----
__global__ __launch_bounds__(256) void quant_x_kernel(const float* __restrict__ x,
                                                      int8_t* __restrict__ xq,
                                                      float* __restrict__ srow) {
  const int tid = threadIdx.x;
  const int row = blockIdx.x * 8 + (tid >> 5);
  const int l   = tid & 31;
  const float* xr = x + (size_t)row * Kdim;
  float4 v[32];
  float m = 0.f;
  #pragma unroll
  for (int j = 0; j < 32; ++j) {
    v[j] = *reinterpret_cast<const float4*>(xr + (size_t)(j * 32 + l) * 4);
    m = fmaxf(m, fmaxf(fmaxf(fabsf(v[j].x), fabsf(v[j].y)),
                       fmaxf(fabsf(v[j].z), fabsf(v[j].w))));
  }
  #pragma unroll
  for (int s = 16; s >= 1; s >>= 1) m = fmaxf(m, __shfl_xor(m, s, 64));
  const float rs = (m > 0.f) ? (127.0f / m) : 0.f;
  if (l == 0) srow[row] = m * (1.0f / 127.0f);
  uint32_t* xq32 = reinterpret_cast<uint32_t*>(xq + (size_t)row * Kdim);
  #pragma unroll
  for (int j = 0; j < 32; ++j) {
    int a0 = (int)rintf(v[j].x * rs), a1 = (int)rintf(v[j].y * rs);
    int a2 = (int)rintf(v[j].z * rs), a3 = (int)rintf(v[j].w * rs);
    uint32_t p = (uint32_t)(a0 & 255) | ((uint32_t)(a1 & 255) << 8) |
                 ((uint32_t)(a2 & 255) << 16) | ((uint32_t)(a3 & 255) << 24);
    xq32[j * 32 + l] = p;
  }
}

// ---- prepass 2: w [K][N] fp32 -> wsT [N][K] i8 = sign(w), LDS transpose ----
__global__ __launch_bounds__(256) void sign_w_kernel(const float* __restrict__ w,
                                                     int8_t* __restrict__ wsT) {
  __shared__ int8_t t[64 * 68];
  const int bid = blockIdx.x;
  const int k0 = (bid & 63) * 64;
  const int n0 = (bid >> 6) * 64;
  const int tid = threadIdx.x;
  #pragma unroll
  for (int r = 0; r < 4; ++r) {
    int c  = r * 256 + tid;
    int k  = c >> 4;
    int n4 = (c & 15) * 4;
    float4 v = *reinterpret_cast<const float4*>(w + (size_t)(k0 + k) * Ndim + n0 + n4);
    int s0 = (v.x > 0.f) - (v.x < 0.f);
    int s1 = (v.y > 0.f) - (v.y < 0.f);
    int s2 = (v.z > 0.f) - (v.z < 0.f);
    int s3 = (v.w > 0.f) - (v.w < 0.f);
    uint32_t p = (uint32_t)(s0 & 255) | ((uint32_t)(s1 & 255) << 8) |
                 ((uint32_t)(s2 & 255) << 16) | ((uint32_t)(s3 & 255) << 24);
    *reinterpret_cast<uint32_t*>(&t[k * 68 + n4]) = p;
  }
  __syncthreads();
  const int n  = tid & 63;
  const int ck = (tid >> 6) * 16;
  union { int8_t b[16]; uint4 u; } o;
  #pragma unroll
  for (int j = 0; j < 16; ++j) o.b[j] = t[(ck + j) * 68 + n];
  *reinterpret_cast<uint4*>(wsT + (size_t)(n0 + n) * Kdim + k0 + ck) = o.u;
}

// ---- main GEMM: i8, 32x32x32 MFMA, BK=128B, XOR-swizzled LDS ----
__global__ __launch_bounds__(256, 4) void gemm_i8_kernel(const int8_t* __restrict__ A,
                                                         const int8_t* __restrict__ Bt,
                                                         const float* __restrict__ srow,
                                                         const float* __restrict__ bias,
                                                         float* __restrict__ out) {
  __shared__ int8_t sA[BM * BKB];   // 16 KB; slot s=(row<<3|c'), holds chunk c'^(row&7)
  __shared__ int8_t sB[BN * BKB];   // 16 KB
  const int tid  = threadIdx.x;
  const int bn   = blockIdx.x, bm = blockIdx.y;
  const int lane = tid & 63;
  const int wave = tid >> 6;
  const int wm   = (wave & 1) * 64;   // wave 64x64 sub-tile origin
  const int wn   = (wave >> 1) * 64;
  const int m    = lane & 31;         // MFMA row/col index
  const int h    = lane >> 5;         // k-half selector
  const int em   = m & 7;             // swizzle key (wm, i*32 are mult of 8)

  // staging: 4 slots/thread/matrix; lane reads the pre-swizzled global chunk
  const int8_t* gAp[4];
  const int8_t* gBp[4];
  #pragma unroll
  for (int p = 0; p < 4; ++p) {
    int s  = tid + 256 * p;
    int r  = s >> 3;
    int cg = (s & 7) ^ (r & 7);
    gAp[p] = A  + (size_t)(bm * BM + r) * Kdim + cg * 16;
    gBp[p] = Bt + (size_t)(bn * BN + r) * Kdim + cg * 16;
  }

  i32x16 acc[2][2] = {};

  for (int k0 = 0; k0 < Kdim; k0 += BKB) {
    #pragma unroll
    for (int p = 0; p < 4; ++p) {
      async_copy16(gAp[p] + k0, &sA[(tid + 256 * p) * 16]);
      async_copy16(gBp[p] + k0, &sB[(tid + 256 * p) * 16]);
    }
    __syncthreads();

    #pragma unroll
    for (int ks = 0; ks < 4; ++ks) {
      const int cx = ((ks * 2 + h) ^ em) * 16;   // swizzled byte offset in row
      i32x4 af[2], bf[2];
      #pragma unroll
      for (int i = 0; i < 2; ++i)
        af[i] = *reinterpret_cast<const i32x4*>(&sA[(wm + i * 32 + m) * BKB + cx]);
      #pragma unroll
      for (int j = 0; j < 2; ++j)
        bf[j] = *reinterpret_cast<const i32x4*>(&sB[(wn + j * 32 + m) * BKB + cx]);
      #pragma unroll
      for (int i = 0; i < 2; ++i)
        #pragma unroll
        for (int j = 0; j < 2; ++j)
          acc[i][j] = __builtin_amdgcn_mfma_i32_32x32x32_i8(af[i], bf[j], acc[i][j], 0, 0, 0);
    }
    __syncthreads();
  }

  // epilogue: C/D 32x32 layout col=lane&31, row=(reg&3)+8*(reg>>2)+4*h
  float bv[2];
  #pragma unroll
  for (int j = 0; j < 2; ++j) bv[j] = bias[bn * BN + wn + j * 32 + m];
  #pragma unroll
  for (int i = 0; i < 2; ++i) {
    const int base_row = bm * BM + wm + i * 32 + 4 * h;
    #pragma unroll
    for (int gg = 0; gg < 4; ++gg) {
      float sv[4];
      #pragma unroll
      for (int rr = 0; rr < 4; ++rr) sv[rr] = srow[base_row + gg * 8 + rr];
      #pragma unroll
      for (int j = 0; j < 2; ++j) {
        const int col = bn * BN + wn + j * 32 + m;
        #pragma unroll
        for (int rr = 0; rr < 4; ++rr) {
          const int reg = gg * 4 + rr;
          out[(size_t)(base_row + gg * 8 + rr) * Ndim + col] =
              (float)acc[i][j][reg] * sv[rr] + bv[j];
        }
      }
    }
  }
}

// ---- fallback (no workspace): fused bf16 convert/binarize staging ----
__global__ __launch_bounds__(256) void gemm_fused_kernel(const float* __restrict__ X,
                                                         const float* __restrict__ W,
                                                         const float* __restrict__ bias,
                                                         float* __restrict__ out) {
  __shared__ __hip_bfloat16 sA[BM * 32];
  __shared__ __hip_bfloat16 sB[BN * 32];
  const int tid  = threadIdx.x;
  const int bn   = blockIdx.x, bm = blockIdx.y;
  const int lane = tid & 63;
  const int wave = tid >> 6;
  const int wm   = (wave & 1) * 64;
  const int wn   = (wave >> 1) * 64;
  const int lr   = lane & 15;
  const int quad = lane >> 4;

  f32x4 acc[4][4] = {};

  for (int k0 = 0; k0 < Kdim; k0 += 32) {
    #pragma unroll
    for (int r = 0; r < 2; ++r) {
      int c = r * 256 + tid;
      int row = c >> 2, col = (c & 3) * 8;
      const float4* p = reinterpret_cast<const float4*>(X + (size_t)(bm * BM + row) * Kdim + k0 + col);
      float4 v0 = p[0], v1 = p[1];
      float va[8] = {v0.x, v0.y, v0.z, v0.w, v1.x, v1.y, v1.z, v1.w};
      union { __hip_bfloat16 h[8]; uint4 u; } oa;
      #pragma unroll
      for (int u2 = 0; u2 < 8; ++u2) oa.h[u2] = __float2bfloat16(va[u2]);
      *reinterpret_cast<uint4*>(&sA[c * 8]) = oa.u;

      int kl = c >> 4, n8 = (c & 15) * 8;
      const float4* q = reinterpret_cast<const float4*>(W + (size_t)(k0 + kl) * Ndim + bn * BN + n8);
      float4 w0 = q[0], w1 = q[1];
      float wv[8] = {w0.x, w0.y, w0.z, w0.w, w1.x, w1.y, w1.z, w1.w};
      #pragma unroll
      for (int u2 = 0; u2 < 8; ++u2) {
        float sg = (wv[u2] > 0.f) ? 1.f : ((wv[u2] < 0.f) ? -1.f : 0.f);
        sB[(n8 + u2) * 32 + kl] = __float2bfloat16(sg);
      }
    }
    __syncthreads();

    bf16x8 af[4], bf[4];
    #pragma unroll
    for (int i = 0; i < 4; ++i)
      af[i] = *reinterpret_cast<const bf16x8*>(&sA[(wm + i * 16 + lr) * 32 + quad * 8]);
    #pragma unroll
    for (int j = 0; j < 4; ++j)
      bf[j] = *reinterpret_cast<const bf16x8*>(&sB[(wn + j * 16 + lr) * 32 + quad * 8]);
    #pragma unroll
    for (int i = 0; i < 4; ++i)
      #pragma unroll
      for (int j = 0; j < 4; ++j)
        acc[i][j] = __builtin_amdgcn_mfma_f32_16x16x32_bf16(af[i], bf[j], acc[i][j], 0, 0, 0);
    __syncthreads();
  }

  float bv[4];
  #pragma unroll
  for (int j = 0; j < 4; ++j) bv[j] = bias[bn * BN + wn + j * 16 + lr];
  #pragma unroll
  for (int i = 0; i < 4; ++i) {
    const size_t rowb = (size_t)(bm * BM + wm + i * 16 + quad * 4);
    #pragma unroll
    for (int j = 0; j < 4; ++j) {
      const int col = bn * BN + wn + j * 16 + lr;
      float* o = out + rowb * Ndim + col;
      #pragma unroll
      for (int r = 0; r < 4; ++r)
        o[(size_t)r * Ndim] = acc[i][j][r] + bv[j];
    }
  }
}

extern "C" void kernel_launch(void* const* d_in, const int* in_sizes, int n_in,
                              void* d_out, int out_size, void* d_ws, size_t ws_size,
                              hipStream_t stream) {
  const float* x = (const float*)d_in[0];   // [8192,4096]
  const float* w = (const float*)d_in[1];   // [4096,4096]
  const float* b = (const float*)d_in[2];   // [4096]
  float* out = (float*)d_out;

  const size_t xq_bytes = (size_t)Mdim * Kdim;        // 32 MiB
  const size_t wt_bytes = (size_t)Ndim * Kdim;        // 16 MiB
  const size_t sr_bytes = (size_t)Mdim * sizeof(float);
  const size_t need = xq_bytes + wt_bytes + sr_bytes;

  if (ws_size >= need) {
    int8_t* xq  = (int8_t*)d_ws;
    int8_t* wsT = (int8_t*)((char*)d_ws + xq_bytes);
    float* srow = (float*)((char*)d_ws + xq_bytes + wt_bytes);
    quant_x_kernel<<<Mdim / 8, 256, 0, stream>>>(x, xq, srow);
    sign_w_kernel<<<(Kdim / 64) * (Ndim / 64), 256, 0, stream>>>(w, wsT);
    gemm_i8_kernel<<<dim3(Ndim / BN, Mdim / BM), 256, 0, stream>>>(xq, wsT, srow, b, out);
  } else {
    gemm_fused_kernel<<<dim3(Ndim / BN, Mdim / BM), 256, 0, stream>>>(x, w, b, out);
  }
}